// Round 4
// baseline (193.454 us; speedup 1.0000x reference)
//
#include <hip/hip_runtime.h>

constexpr int B = 32;
constexpr int N = 32 * 32 * 32 + 1;   // 32769
constexpr int K = 32 * 3 * 3;         // 288
constexpr int KQ = K / 4;             // 72 ints per row-quarter (288 B)
constexpr int NSPLIT = 4;

using i4 = __attribute__((ext_vector_type(4))) int;
using f4 = __attribute__((ext_vector_type(4))) float;

// ---------------------------------------------------------------------------
// Kernel 1: transpose x (B,N) -> xT (N,B). 32x32 tiles via LDS.
// ---------------------------------------------------------------------------
__global__ __launch_bounds__(256) void transpose_x_kernel(
    const float* __restrict__ x, float* __restrict__ xT) {
  __shared__ float tile[32][33];
  const int n0 = blockIdx.x * 32;
  const int t  = threadIdx.x;
  const int lb = t & 31;   // 0..31
  const int lr = t >> 5;   // 0..7
#pragma unroll
  for (int i = 0; i < 4; ++i) {
    const int b = lr + i * 8;
    const int n = n0 + lb;
    float v = 0.f;
    if (n < N) v = x[(size_t)b * N + n];   // coalesced over lb
    tile[lb][b] = v;
  }
  __syncthreads();
#pragma unroll
  for (int i = 0; i < 4; ++i) {
    const int nl = lr + i * 8;
    const int n  = n0 + nl;
    if (n < N) xT[(size_t)n * B + lb] = tile[nl][lb];  // coalesced over lb
  }
}

// ---------------------------------------------------------------------------
// Kernel 2: gather-dot, K split x4. Block (bx,q) computes, for 32 n's,
//   yTq[n][b] = sum_{k in quarter q} xT[cols[n,k]][b] * vals[n,k]
// BOTH cols and vals quarters are staged into LDS with global_load_lds so the
// vmcnt queue during compute holds ONLY the xT gathers (uniform L2 latency,
// no in-order head-of-line blocking from HBM stream misses).
// 8-lane group per n; lane owns 4 consecutive b. 18.4 KB LDS -> 8 blocks/CU.
// ---------------------------------------------------------------------------
__global__ __launch_bounds__(256, 8) void gather_dot_q_kernel(
    const float* __restrict__ xT, const float* __restrict__ vals,
    const int* __restrict__ cols, float* __restrict__ yT) {
  __shared__ int   scols[32 * KQ];   // 9216 B
  __shared__ float svals[32 * KQ];   // 9216 B

  const int t    = threadIdx.x;
  const int lane = t & 63;
  const int wave = t >> 6;
  const int g    = lane >> 3;        // 0..7 : n within wave
  const int bq   = lane & 7;         // 0..7 : b quad
  const int n0   = blockIdx.x * 32;
  const int q    = blockIdx.y;       // K quarter
  const int k0   = q * KQ;

  // --- Stage cols+vals quarters. 32 rows x 18 chunks(16B) = 576 chunks. ---
  // chunk c -> row = c/18, 16B-offset within row = c%18.
  // Rounds: r=0,1 full (256 chunks each), r=2 covers chunks 512..575 (wave 0).
  {
    const int nrow_clamp = N - 1;
#pragma unroll
    for (int r = 0; r < 2; ++r) {
      const int c   = r * 256 + t;
      const int row = c / 18;
      const int off = c - row * 18;          // 16B units
      const int nn  = (n0 + row <= nrow_clamp) ? (n0 + row) : nrow_clamp;
      const size_t gi = (size_t)nn * K + k0 + off * 4;   // element index
      __builtin_amdgcn_global_load_lds(
          (const __attribute__((address_space(1))) void*)(cols + gi),
          (__attribute__((address_space(3))) void*)((char*)scols + c * 16),
          16, 0, 0);
      __builtin_amdgcn_global_load_lds(
          (const __attribute__((address_space(1))) void*)(vals + gi),
          (__attribute__((address_space(3))) void*)((char*)svals + c * 16),
          16, 0, 0);
    }
    if (t < 64) {   // wave 0 only: chunks 512..575
      const int c   = 512 + t;
      const int row = c / 18;
      const int off = c - row * 18;
      const int nn  = (n0 + row <= nrow_clamp) ? (n0 + row) : nrow_clamp;
      const size_t gi = (size_t)nn * K + k0 + off * 4;
      __builtin_amdgcn_global_load_lds(
          (const __attribute__((address_space(1))) void*)(cols + gi),
          (__attribute__((address_space(3))) void*)((char*)scols + c * 16),
          16, 0, 0);
      __builtin_amdgcn_global_load_lds(
          (const __attribute__((address_space(1))) void*)(vals + gi),
          (__attribute__((address_space(3))) void*)((char*)svals + c * 16),
          16, 0, 0);
    }
  }
  __syncthreads();   // drains vmcnt -> LDS valid

  const int nl = wave * 8 + g;
  const int n  = n0 + nl;
  if (n >= N) return;

  const int*   __restrict__ srow = scols + nl * KQ;
  const float* __restrict__ vrow = svals + nl * KQ;

  f4 acc0 = {0.f, 0.f, 0.f, 0.f};
  f4 acc1 = {0.f, 0.f, 0.f, 0.f};

  const int rot = g * 8;   // bank-spread rotation, multiple of 8 (KQ%8==0)

#pragma unroll 3
  for (int k = 0; k < KQ; k += 8) {            // 9 iterations
    int kk = k + rot;
    if (kk >= KQ) kk -= KQ;

    const i4 c0 = *reinterpret_cast<const i4*>(srow + kk);      // ds_read_b128
    const i4 c1 = *reinterpret_cast<const i4*>(srow + kk + 4);
    const f4 v0 = *reinterpret_cast<const f4*>(vrow + kk);
    const f4 v1 = *reinterpret_cast<const f4*>(vrow + kk + 4);

    const f4 x0 = *reinterpret_cast<const f4*>(xT + (size_t)c0.x * B + bq * 4);
    const f4 x1 = *reinterpret_cast<const f4*>(xT + (size_t)c0.y * B + bq * 4);
    const f4 x2 = *reinterpret_cast<const f4*>(xT + (size_t)c0.z * B + bq * 4);
    const f4 x3 = *reinterpret_cast<const f4*>(xT + (size_t)c0.w * B + bq * 4);
    const f4 x4 = *reinterpret_cast<const f4*>(xT + (size_t)c1.x * B + bq * 4);
    const f4 x5 = *reinterpret_cast<const f4*>(xT + (size_t)c1.y * B + bq * 4);
    const f4 x6 = *reinterpret_cast<const f4*>(xT + (size_t)c1.z * B + bq * 4);
    const f4 x7 = *reinterpret_cast<const f4*>(xT + (size_t)c1.w * B + bq * 4);

    acc0 += x0 * v0.x;
    acc0 += x1 * v0.y;
    acc0 += x2 * v0.z;
    acc0 += x3 * v0.w;
    acc1 += x4 * v1.x;
    acc1 += x5 * v1.y;
    acc1 += x6 * v1.z;
    acc1 += x7 * v1.w;
  }

  acc0 += acc1;
  // Non-temporal: partials are read once by the sum kernel; keep L2 for xT.
  __builtin_nontemporal_store(
      acc0, reinterpret_cast<f4*>(yT + (size_t)q * N * B + (size_t)n * B + bq * 4));
}

// ---------------------------------------------------------------------------
// Kernel 3: y (B,N) = transpose(sum of 4 yT partials (N,B)).
// ---------------------------------------------------------------------------
__global__ __launch_bounds__(256) void transpose_y_sum4_kernel(
    const float* __restrict__ yT, float* __restrict__ y) {
  __shared__ float tile[32][33];
  const int n0 = blockIdx.x * 32;
  const int t  = threadIdx.x;
  const int lb = t & 31;
  const int lr = t >> 5;
  constexpr size_t NB = (size_t)N * B;
#pragma unroll
  for (int i = 0; i < 4; ++i) {
    const int nl = lr + i * 8;
    const int n  = n0 + nl;
    float v = 0.f;
    if (n < N) {
      const size_t idx = (size_t)n * B + lb;
      v = yT[idx] + yT[NB + idx] + yT[2 * NB + idx] + yT[3 * NB + idx];
    }
    tile[nl][lb] = v;
  }
  __syncthreads();
#pragma unroll
  for (int i = 0; i < 4; ++i) {
    const int b = lr + i * 8;
    const int n = n0 + lb;
    if (n < N) y[(size_t)b * N + n] = tile[lb][b];  // coalesced over lb
  }
}

// ---------------------------------------------------------------------------
// Fallback (ws too small): direct strided gather, correct but slow.
// ---------------------------------------------------------------------------
__global__ __launch_bounds__(256) void gather_dot_fallback(
    const float* __restrict__ x, const float* __restrict__ vals,
    const int* __restrict__ cols, float* __restrict__ y) {
  const int t    = threadIdx.x;
  const int lane = t & 63;
  const int wave = t >> 6;
  const int g    = lane >> 3;
  const int bq   = lane & 7;
  const int n    = blockIdx.x * 32 + wave * 8 + g;
  if (n >= N) return;
  const int*   crow = cols + (size_t)n * K;
  const float* vrow = vals + (size_t)n * K;
  float4 acc = make_float4(0.f, 0.f, 0.f, 0.f);
  for (int k = 0; k < K; ++k) {
    const int   c = crow[k];
    const float v = vrow[k];
    acc.x += x[(size_t)(bq * 4 + 0) * N + c] * v;
    acc.y += x[(size_t)(bq * 4 + 1) * N + c] * v;
    acc.z += x[(size_t)(bq * 4 + 2) * N + c] * v;
    acc.w += x[(size_t)(bq * 4 + 3) * N + c] * v;
  }
  y[(size_t)(bq * 4 + 0) * N + n] = acc.x;
  y[(size_t)(bq * 4 + 1) * N + n] = acc.y;
  y[(size_t)(bq * 4 + 2) * N + n] = acc.z;
  y[(size_t)(bq * 4 + 3) * N + n] = acc.w;
}

extern "C" void kernel_launch(void* const* d_in, const int* in_sizes, int n_in,
                              void* d_out, int out_size, void* d_ws, size_t ws_size,
                              hipStream_t stream) {
  const float* x    = (const float*)d_in[0];   // x_affine (B,N)
  const float* vals = (const float*)d_in[1];   // (N,K)
  const int*   cols = (const int*)d_in[2];     // (N,K)
  float*       y    = (float*)d_out;           // (B,N)

  const size_t nb_elems = (size_t)N * B;                            // 4.19 MB
  const size_t need = (1 + NSPLIT) * nb_elems * sizeof(float);      // xT + 4 partials

  const int nblocks = (N + 31) / 32;   // 1025

  if (ws_size >= need) {
    float* xT = (float*)d_ws;
    float* yT = xT + nb_elems;           // 4 partials, contiguous
    transpose_x_kernel<<<nblocks, 256, 0, stream>>>(x, xT);
    dim3 grid(nblocks, NSPLIT);
    gather_dot_q_kernel<<<grid, 256, 0, stream>>>(xT, vals, cols, yT);
    transpose_y_sum4_kernel<<<nblocks, 256, 0, stream>>>(yT, y);
  } else {
    gather_dot_fallback<<<nblocks, 256, 0, stream>>>(x, vals, cols, y);
  }
}

// Round 5
// 174.054 us; speedup vs baseline: 1.1115x; 1.1115x over previous
//
#include <hip/hip_runtime.h>

constexpr int B = 32;
constexpr int N = 32 * 32 * 32 + 1;   // 32769
constexpr int K = 32 * 3 * 3;         // 288

using i4 = __attribute__((ext_vector_type(4))) int;
using f4 = __attribute__((ext_vector_type(4))) float;
using h4 = __attribute__((ext_vector_type(4))) _Float16;

// ---------------------------------------------------------------------------
// Kernel 1: transpose + downconvert x (B,N) fp32 -> xT (N,B) fp16 (2.1 MB).
// xT row = 64 B; the whole table is L2-resident per XCD (4 MiB).
// ---------------------------------------------------------------------------
__global__ __launch_bounds__(256) void transpose_x_f16_kernel(
    const float* __restrict__ x, _Float16* __restrict__ xT) {
  __shared__ float tile[32][33];
  const int n0 = blockIdx.x * 32;
  const int t  = threadIdx.x;
  const int lb = t & 31;   // 0..31
  const int lr = t >> 5;   // 0..7
#pragma unroll
  for (int i = 0; i < 4; ++i) {
    const int b = lr + i * 8;
    const int n = n0 + lb;
    float v = 0.f;
    if (n < N) v = x[(size_t)b * N + n];   // coalesced over lb
    tile[lb][b] = v;
  }
  __syncthreads();
#pragma unroll
  for (int i = 0; i < 4; ++i) {
    const int nl = lr + i * 8;
    const int n  = n0 + nl;
    if (n < N) xT[(size_t)n * B + lb] = (_Float16)tile[nl][lb];  // 2B, 64B/row
  }
}

// ---------------------------------------------------------------------------
// Kernel 2: gather-dot. yT[n][b] = sum_k (float)xT16[cols[n,k]][b] * vals[n,k]
// 8-lane group per n (32 n / 256-thread block); lane owns 4 consecutive b
// (8 B fp16 gather -> one 64 B L2 granule per (n,k) for all 32 b).
// cols staged to LDS via global_load_lds (vmcnt queue stays clean of the
// stream); group g rotates k-start by g*8 to spread LDS banks (stride-288
// rows alias otherwise). vals loads are off the critical (address) path.
// ---------------------------------------------------------------------------
__global__ __launch_bounds__(256, 4) void gather_dot_f16_kernel(
    const _Float16* __restrict__ xT, const float* __restrict__ vals,
    const int* __restrict__ cols, float* __restrict__ yT) {
  __shared__ int scols[32 * K];              // 36864 B -> 4 blocks/CU
  const int t    = threadIdx.x;
  const int lane = t & 63;
  const int wave = t >> 6;
  const int g    = lane >> 3;        // 0..7 : n within wave
  const int bq   = lane & 7;         // 0..7 : b quad
  const int n0   = blockIdx.x * 32;

  // --- Stage the block's cols slab (contiguous 32*K ints) into LDS. ---
  constexpr int SLAB_BYTES = 32 * K * 4;         // 36864
  constexpr int ROUNDS     = SLAB_BYTES / 4096;  // 9 (256 thr * 16 B)
  const char* slab = (const char*)(cols + (size_t)n0 * K);
  const long long avail = ((long long)N * K - (long long)n0 * K) * 4;
#pragma unroll
  for (int r = 0; r < ROUNDS; ++r) {
    const int off  = r * 4096 + t * 16;
    const int goff = (off + 16 <= avail) ? off : 0;   // clamp past end of cols
    __builtin_amdgcn_global_load_lds(
        (const __attribute__((address_space(1))) void*)(slab + goff),
        (__attribute__((address_space(3))) void*)((char*)scols + off),
        16, 0, 0);
  }
  __syncthreads();   // drains vmcnt -> LDS valid

  const int nl = wave * 8 + g;
  const int n  = n0 + nl;
  if (n >= N) return;

  const int*   __restrict__ srow = scols + nl * K;
  const float* __restrict__ vrow = vals + (size_t)n * K;

  f4 acc0 = {0.f, 0.f, 0.f, 0.f};
  f4 acc1 = {0.f, 0.f, 0.f, 0.f};

  const int rot = g * 8;   // bank-spread rotation (multiple of 8 ints)

#pragma unroll 4
  for (int k = 0; k < K; k += 8) {             // 36 iterations
    int kk = k + rot;
    if (kk >= K) kk -= K;

    const i4 c0 = *reinterpret_cast<const i4*>(srow + kk);      // ds_read_b128
    const i4 c1 = *reinterpret_cast<const i4*>(srow + kk + 4);
    const f4 v0 = *reinterpret_cast<const f4*>(vrow + kk);
    const f4 v1 = *reinterpret_cast<const f4*>(vrow + kk + 4);

    const h4 x0 = *reinterpret_cast<const h4*>(xT + (size_t)c0.x * B + bq * 4);
    const h4 x1 = *reinterpret_cast<const h4*>(xT + (size_t)c0.y * B + bq * 4);
    const h4 x2 = *reinterpret_cast<const h4*>(xT + (size_t)c0.z * B + bq * 4);
    const h4 x3 = *reinterpret_cast<const h4*>(xT + (size_t)c0.w * B + bq * 4);
    const h4 x4 = *reinterpret_cast<const h4*>(xT + (size_t)c1.x * B + bq * 4);
    const h4 x5 = *reinterpret_cast<const h4*>(xT + (size_t)c1.y * B + bq * 4);
    const h4 x6 = *reinterpret_cast<const h4*>(xT + (size_t)c1.z * B + bq * 4);
    const h4 x7 = *reinterpret_cast<const h4*>(xT + (size_t)c1.w * B + bq * 4);

    acc0 += __builtin_convertvector(x0, f4) * v0.x;
    acc0 += __builtin_convertvector(x1, f4) * v0.y;
    acc0 += __builtin_convertvector(x2, f4) * v0.z;
    acc0 += __builtin_convertvector(x3, f4) * v0.w;
    acc1 += __builtin_convertvector(x4, f4) * v1.x;
    acc1 += __builtin_convertvector(x5, f4) * v1.y;
    acc1 += __builtin_convertvector(x6, f4) * v1.z;
    acc1 += __builtin_convertvector(x7, f4) * v1.w;
  }

  acc0 += acc1;
  *reinterpret_cast<f4*>(yT + (size_t)n * B + bq * 4) = acc0;   // plain store
}

// ---------------------------------------------------------------------------
// Kernel 3: transpose yT (N,B) -> y (B,N).
// ---------------------------------------------------------------------------
__global__ __launch_bounds__(256) void transpose_y_kernel(
    const float* __restrict__ yT, float* __restrict__ y) {
  __shared__ float tile[32][33];
  const int n0 = blockIdx.x * 32;
  const int t  = threadIdx.x;
  const int lb = t & 31;
  const int lr = t >> 5;
#pragma unroll
  for (int i = 0; i < 4; ++i) {
    const int nl = lr + i * 8;
    const int n  = n0 + nl;
    float v = 0.f;
    if (n < N) v = yT[(size_t)n * B + lb];   // coalesced over lb
    tile[nl][lb] = v;
  }
  __syncthreads();
#pragma unroll
  for (int i = 0; i < 4; ++i) {
    const int b = lr + i * 8;
    const int n = n0 + lb;
    if (n < N) y[(size_t)b * N + n] = tile[lb][b];  // coalesced over lb
  }
}

// ---------------------------------------------------------------------------
// Fallback (ws too small): direct strided gather, fp32, correct but slow.
// ---------------------------------------------------------------------------
__global__ __launch_bounds__(256) void gather_dot_fallback(
    const float* __restrict__ x, const float* __restrict__ vals,
    const int* __restrict__ cols, float* __restrict__ y) {
  const int t    = threadIdx.x;
  const int lane = t & 63;
  const int wave = t >> 6;
  const int g    = lane >> 3;
  const int bq   = lane & 7;
  const int n    = blockIdx.x * 32 + wave * 8 + g;
  if (n >= N) return;
  const int*   crow = cols + (size_t)n * K;
  const float* vrow = vals + (size_t)n * K;
  float4 acc = make_float4(0.f, 0.f, 0.f, 0.f);
  for (int k = 0; k < K; ++k) {
    const int   c = crow[k];
    const float v = vrow[k];
    acc.x += x[(size_t)(bq * 4 + 0) * N + c] * v;
    acc.y += x[(size_t)(bq * 4 + 1) * N + c] * v;
    acc.z += x[(size_t)(bq * 4 + 2) * N + c] * v;
    acc.w += x[(size_t)(bq * 4 + 3) * N + c] * v;
  }
  y[(size_t)(bq * 4 + 0) * N + n] = acc.x;
  y[(size_t)(bq * 4 + 1) * N + n] = acc.y;
  y[(size_t)(bq * 4 + 2) * N + n] = acc.z;
  y[(size_t)(bq * 4 + 3) * N + n] = acc.w;
}

extern "C" void kernel_launch(void* const* d_in, const int* in_sizes, int n_in,
                              void* d_out, int out_size, void* d_ws, size_t ws_size,
                              hipStream_t stream) {
  const float* x    = (const float*)d_in[0];   // x_affine (B,N)
  const float* vals = (const float*)d_in[1];   // (N,K)
  const int*   cols = (const int*)d_in[2];     // (N,K)
  float*       y    = (float*)d_out;           // (B,N)

  const size_t nb       = (size_t)N * B;
  const size_t xT_bytes = nb * sizeof(_Float16);          // 2.1 MB
  const size_t need     = xT_bytes + nb * sizeof(float);  // + yT 4.19 MB

  const int nblocks = (N + 31) / 32;   // 1025

  if (ws_size >= need) {
    _Float16* xT = (_Float16*)d_ws;
    float*    yT = (float*)((char*)d_ws + xT_bytes);   // 4B-aligned (even off)
    transpose_x_f16_kernel<<<nblocks, 256, 0, stream>>>(x, xT);
    gather_dot_f16_kernel<<<nblocks, 256, 0, stream>>>(xT, vals, cols, yT);
    transpose_y_kernel<<<nblocks, 256, 0, stream>>>(yT, y);
  } else {
    gather_dot_fallback<<<nblocks, 256, 0, stream>>>(x, vals, cols, y);
  }
}

// Round 6
// 173.380 us; speedup vs baseline: 1.1158x; 1.0039x over previous
//
#include <hip/hip_runtime.h>

constexpr int B = 32;
constexpr int N = 32 * 32 * 32 + 1;   // 32769
constexpr int K = 32 * 3 * 3;         // 288

using i4 = __attribute__((ext_vector_type(4))) int;
using f4 = __attribute__((ext_vector_type(4))) float;
using h4 = __attribute__((ext_vector_type(4))) _Float16;

// ---------------------------------------------------------------------------
// Kernel 1: transpose + downconvert x (B,N) fp32 -> xT (N,B) fp16 (2.1 MB).
// 64 B per row; table is L2-resident per XCD.
// ---------------------------------------------------------------------------
__global__ __launch_bounds__(256) void transpose_x_f16_kernel(
    const float* __restrict__ x, _Float16* __restrict__ xT) {
  __shared__ float tile[32][33];
  const int n0 = blockIdx.x * 32;
  const int t  = threadIdx.x;
  const int lb = t & 31;   // 0..31
  const int lr = t >> 5;   // 0..7
#pragma unroll
  for (int i = 0; i < 4; ++i) {
    const int b = lr + i * 8;
    const int n = n0 + lb;
    float v = 0.f;
    if (n < N) v = x[(size_t)b * N + n];   // coalesced over lb
    tile[lb][b] = v;
  }
  __syncthreads();
#pragma unroll
  for (int i = 0; i < 4; ++i) {
    const int nl = lr + i * 8;
    const int n  = n0 + nl;
    if (n < N) xT[(size_t)n * B + lb] = (_Float16)tile[nl][lb];
  }
}

// ---------------------------------------------------------------------------
// Kernel 2: gather-dot. yT[n][b] = sum_k (float)xT16[cols[n,k]][b] * vals[n,k]
// cols packed to u16 in LDS (18.4 KB -> 8 blocks/CU, 32 waves/CU).
// 8-lane group per n; lane owns 4 consecutive b (8 B gather = 1 64 B line
// per (n,k) for all 32 b). 32-bit voffset addressing: per-lane base xT+bq*8,
// per-gather offset = (packed<<6)&0x3FFFC0 (2 VALU). Group g rotates k by g*8
// -> the 8 concurrent ds_read_b128 land on disjoint bank spans.
// ---------------------------------------------------------------------------
__global__ __launch_bounds__(256, 8) void gather_dot_f16_u16_kernel(
    const _Float16* __restrict__ xT, const float* __restrict__ vals,
    const int* __restrict__ cols, float* __restrict__ yT) {
  __shared__ unsigned short scols[32 * K];   // 18432 B
  const int t    = threadIdx.x;
  const int lane = t & 63;
  const int wave = t >> 6;
  const int g    = lane >> 3;        // 0..7 : n within wave
  const int bq   = lane & 7;         // 0..7 : b quad
  const int n0   = blockIdx.x * 32;

  // --- Stage cols slab as u16: each thread packs 9 int4 -> 9 x 8B writes. ---
  {
    const long long last = (long long)N * K - 4;   // last valid int4 start
    unsigned int* sc32 = (unsigned int*)scols;
#pragma unroll
    for (int r = 0; r < 9; ++r) {
      const int c = r * 256 + t;                   // int4 chunk id, 0..2303
      long long gi = (long long)n0 * K + (long long)c * 4;
      if (gi > last) gi = last;                    // clamp (tail block)
      const i4 w = *reinterpret_cast<const i4*>(cols + gi);
      const unsigned int p0 = (unsigned int)(w.x & 0xFFFF) | ((unsigned int)w.y << 16);
      const unsigned int p1 = (unsigned int)(w.z & 0xFFFF) | ((unsigned int)w.w << 16);
      sc32[c * 2]     = p0;
      sc32[c * 2 + 1] = p1;
    }
  }
  __syncthreads();

  const int nl = wave * 8 + g;
  const int n  = n0 + nl;
  if (n >= N) return;

  const unsigned short* __restrict__ srow = scols + nl * K;
  const char* __restrict__ xTb  = (const char*)xT + bq * 8;   // per-lane base
  const char* __restrict__ vrow = (const char*)(vals + (size_t)n * K);

  f4 acc0 = {0.f, 0.f, 0.f, 0.f};
  f4 acc1 = {0.f, 0.f, 0.f, 0.f};

  const int rot = g * 8;   // bank-spread rotation (multiple of 8)

#pragma unroll 4
  for (int k = 0; k < K; k += 8) {             // 36 iterations
    int kk = k + rot;
    if (kk >= K) kk -= K;

    // 8 packed cols in one ds_read_b128
    const i4 cp = *reinterpret_cast<const i4*>(srow + kk);
    const f4 v0 = *reinterpret_cast<const f4*>(vrow + kk * 4);
    const f4 v1 = *reinterpret_cast<const f4*>(vrow + kk * 4 + 16);

    const unsigned int w0 = (unsigned int)cp.x;
    const unsigned int w1 = (unsigned int)cp.y;
    const unsigned int w2 = (unsigned int)cp.z;
    const unsigned int w3 = (unsigned int)cp.w;
    // byte offset = col * 64  (col = lo/hi u16 of each word)
    const unsigned int o0 = (w0 << 6) & 0x3FFFC0u;
    const unsigned int o1 = (w0 >> 10) & 0x3FFFC0u;
    const unsigned int o2 = (w1 << 6) & 0x3FFFC0u;
    const unsigned int o3 = (w1 >> 10) & 0x3FFFC0u;
    const unsigned int o4 = (w2 << 6) & 0x3FFFC0u;
    const unsigned int o5 = (w2 >> 10) & 0x3FFFC0u;
    const unsigned int o6 = (w3 << 6) & 0x3FFFC0u;
    const unsigned int o7 = (w3 >> 10) & 0x3FFFC0u;

    const h4 x0 = *reinterpret_cast<const h4*>(xTb + o0);
    const h4 x1 = *reinterpret_cast<const h4*>(xTb + o1);
    const h4 x2 = *reinterpret_cast<const h4*>(xTb + o2);
    const h4 x3 = *reinterpret_cast<const h4*>(xTb + o3);
    const h4 x4 = *reinterpret_cast<const h4*>(xTb + o4);
    const h4 x5 = *reinterpret_cast<const h4*>(xTb + o5);
    const h4 x6 = *reinterpret_cast<const h4*>(xTb + o6);
    const h4 x7 = *reinterpret_cast<const h4*>(xTb + o7);

    acc0 += __builtin_convertvector(x0, f4) * v0.x;
    acc0 += __builtin_convertvector(x1, f4) * v0.y;
    acc0 += __builtin_convertvector(x2, f4) * v0.z;
    acc0 += __builtin_convertvector(x3, f4) * v0.w;
    acc1 += __builtin_convertvector(x4, f4) * v1.x;
    acc1 += __builtin_convertvector(x5, f4) * v1.y;
    acc1 += __builtin_convertvector(x6, f4) * v1.z;
    acc1 += __builtin_convertvector(x7, f4) * v1.w;
  }

  acc0 += acc1;
  *reinterpret_cast<f4*>(yT + (size_t)n * B + bq * 4) = acc0;
}

// ---------------------------------------------------------------------------
// Kernel 3: transpose yT (N,B) -> y (B,N).
// ---------------------------------------------------------------------------
__global__ __launch_bounds__(256) void transpose_y_kernel(
    const float* __restrict__ yT, float* __restrict__ y) {
  __shared__ float tile[32][33];
  const int n0 = blockIdx.x * 32;
  const int t  = threadIdx.x;
  const int lb = t & 31;
  const int lr = t >> 5;
#pragma unroll
  for (int i = 0; i < 4; ++i) {
    const int nl = lr + i * 8;
    const int n  = n0 + nl;
    float v = 0.f;
    if (n < N) v = yT[(size_t)n * B + lb];   // coalesced over lb
    tile[nl][lb] = v;
  }
  __syncthreads();
#pragma unroll
  for (int i = 0; i < 4; ++i) {
    const int b = lr + i * 8;
    const int n = n0 + lb;
    if (n < N) y[(size_t)b * N + n] = tile[lb][b];  // coalesced over lb
  }
}

// ---------------------------------------------------------------------------
// Fallback (ws too small): direct strided gather, fp32, correct but slow.
// ---------------------------------------------------------------------------
__global__ __launch_bounds__(256) void gather_dot_fallback(
    const float* __restrict__ x, const float* __restrict__ vals,
    const int* __restrict__ cols, float* __restrict__ y) {
  const int t    = threadIdx.x;
  const int lane = t & 63;
  const int wave = t >> 6;
  const int g    = lane >> 3;
  const int bq   = lane & 7;
  const int n    = blockIdx.x * 32 + wave * 8 + g;
  if (n >= N) return;
  const int*   crow = cols + (size_t)n * K;
  const float* vrow = vals + (size_t)n * K;
  float4 acc = make_float4(0.f, 0.f, 0.f, 0.f);
  for (int k = 0; k < K; ++k) {
    const int   c = crow[k];
    const float v = vrow[k];
    acc.x += x[(size_t)(bq * 4 + 0) * N + c] * v;
    acc.y += x[(size_t)(bq * 4 + 1) * N + c] * v;
    acc.z += x[(size_t)(bq * 4 + 2) * N + c] * v;
    acc.w += x[(size_t)(bq * 4 + 3) * N + c] * v;
  }
  y[(size_t)(bq * 4 + 0) * N + n] = acc.x;
  y[(size_t)(bq * 4 + 1) * N + n] = acc.y;
  y[(size_t)(bq * 4 + 2) * N + n] = acc.z;
  y[(size_t)(bq * 4 + 3) * N + n] = acc.w;
}

extern "C" void kernel_launch(void* const* d_in, const int* in_sizes, int n_in,
                              void* d_out, int out_size, void* d_ws, size_t ws_size,
                              hipStream_t stream) {
  const float* x    = (const float*)d_in[0];   // x_affine (B,N)
  const float* vals = (const float*)d_in[1];   // (N,K)
  const int*   cols = (const int*)d_in[2];     // (N,K)
  float*       y    = (float*)d_out;           // (B,N)

  const size_t nb       = (size_t)N * B;
  const size_t xT_bytes = nb * sizeof(_Float16);          // 2.1 MB
  const size_t need     = xT_bytes + nb * sizeof(float);  // + yT 4.19 MB

  const int nblocks = (N + 31) / 32;   // 1025

  if (ws_size >= need) {
    _Float16* xT = (_Float16*)d_ws;
    float*    yT = (float*)((char*)d_ws + xT_bytes);
    transpose_x_f16_kernel<<<nblocks, 256, 0, stream>>>(x, xT);
    gather_dot_f16_u16_kernel<<<nblocks, 256, 0, stream>>>(xT, vals, cols, yT);
    transpose_y_kernel<<<nblocks, 256, 0, stream>>>(yT, y);
  } else {
    gather_dot_fallback<<<nblocks, 256, 0, stream>>>(x, vals, cols, y);
  }
}